// Round 5
// baseline (655.272 us; speedup 1.0000x reference)
//
#include <hip/hip_runtime.h>
#include <hip/hip_bf16.h>
#include <cstdint>

#define N_SAMP 8192
#define IN_DIM 1024
#define HID    2048
#define NE     4

typedef __attribute__((ext_vector_type(8))) __bf16 bf16x8;
typedef __attribute__((ext_vector_type(4))) float  f32x4;

#define MFMA16 __builtin_amdgcn_mfma_f32_16x16x32_bf16

__device__ __forceinline__ unsigned short f2b(float f) {
    unsigned u = __float_as_uint(f);
    u += 0x7fff + ((u >> 16) & 1);          // RNE, finite inputs only
    return (unsigned short)(u >> 16);
}
__device__ __forceinline__ float b2f(unsigned short s) {
    return __uint_as_float(((unsigned)s) << 16);
}

// async global->LDS, 16B per lane; LDS dest is wave-uniform base (+lane*16 by HW)
__device__ __forceinline__ void gll16(const void* g, void* l) {
    __builtin_amdgcn_global_load_lds(
        (const __attribute__((address_space(1))) void*)g,
        (__attribute__((address_space(3))) void*)l,
        16, 0, 0);
}

// ---------------- f32 -> bf16 elementwise ----------------
__global__ void conv_bf16(const float* __restrict__ s, unsigned short* __restrict__ d, int n) {
    int i = (blockIdx.x * blockDim.x + threadIdx.x) * 4;
    if (i >= n) return;
    float4 v = *(const float4*)&s[i];
    ushort4 o;
    o.x = f2b(v.x); o.y = f2b(v.y); o.z = f2b(v.z); o.w = f2b(v.w);
    *(ushort4*)&d[i] = o;
}

// ---------------- transpose + convert: src [K][M] f32 -> dst [M][K] bf16 ----------------
__global__ void transpose_conv(const float* __restrict__ src, unsigned short* __restrict__ dst,
                               int K, int M) {
    __shared__ float tile[64][65];
    const int k0 = blockIdx.x * 64, m0 = blockIdx.y * 64;
    const int t  = threadIdx.x;
    const int tc = t & 15, tr = t >> 4;
    const float* s = src + (size_t)k0 * M + m0;
    #pragma unroll
    for (int r = tr; r < 64; r += 16) {
        float4 v = *(const float4*)&s[(size_t)r * M + tc * 4];
        tile[r][tc * 4 + 0] = v.x; tile[r][tc * 4 + 1] = v.y;
        tile[r][tc * 4 + 2] = v.z; tile[r][tc * 4 + 3] = v.w;
    }
    __syncthreads();
    unsigned short* d = dst + (size_t)m0 * K + k0;
    #pragma unroll
    for (int r = tr; r < 64; r += 16) {
        ushort4 o;
        o.x = f2b(tile[tc * 4 + 0][r]); o.y = f2b(tile[tc * 4 + 1][r]);
        o.z = f2b(tile[tc * 4 + 2][r]); o.w = f2b(tile[tc * 4 + 3][r]);
        *(ushort4*)&d[(size_t)r * K + tc * 4] = o;
    }
}

// ---------------- router: fp32 logits, softmax, first-max argmax, reg_loss ----------------
__global__ void router_kernel(const float* __restrict__ bb, const int* __restrict__ task,
                              const float* __restrict__ temb, const float* __restrict__ rm,
                              float* __restrict__ gval, int* __restrict__ gidx,
                              float* __restrict__ regout) {
    const int t = threadIdx.x, wave = t >> 6, lane = t & 63;
    const int n = blockIdx.x * 4 + wave;
    const int tk = task[n];
    float a0 = 0.f, a1 = 0.f, a2 = 0.f, a3 = 0.f;
    for (int i = lane; i < IN_DIM + 100; i += 64) {
        float x = (i < IN_DIM) ? bb[(size_t)n * IN_DIM + i] : temb[tk * 100 + (i - IN_DIM)];
        float4 r = *(const float4*)&rm[i * 4];
        a0 += x * r.x; a1 += x * r.y; a2 += x * r.z; a3 += x * r.w;
    }
    #pragma unroll
    for (int o = 32; o; o >>= 1) {
        a0 += __shfl_xor(a0, o); a1 += __shfl_xor(a1, o);
        a2 += __shfl_xor(a2, o); a3 += __shfl_xor(a3, o);
    }
    if (lane == 0) {
        float l[4] = {a0, a1, a2, a3};
        float mx = fmaxf(fmaxf(l[0], l[1]), fmaxf(l[2], l[3]));
        float ex[4], s = 0.f;
        #pragma unroll
        for (int j = 0; j < 4; j++) { ex[j] = expf(l[j] - mx); s += ex[j]; }
        int bi = 0; float bw = ex[0];
        #pragma unroll
        for (int j = 1; j < 4; j++) if (ex[j] > bw) { bw = ex[j]; bi = j; }
        float g = bw / s;
        gval[n] = g;
        gidx[n] = bi;
        regout[n] = -0.0025f * (logf(g + 1e-6f) + 3.0f * logf(1e-6f));
    }
}

// ---------------- per-expert compaction: list_e = {n : idx[n] >= e}; pad to mult 256 --------
__global__ void compact_kernel(const int* __restrict__ gidx, int* __restrict__ list,
                               int* __restrict__ pos, int* __restrict__ cnt) {
    const int e = blockIdx.x;
    const int t = threadIdx.x, lane = t & 63, wave = t >> 6;
    __shared__ int wbase[4];
    __shared__ int running;
    if (t == 0) running = 0;
    __syncthreads();
    int* le = list + (size_t)e * N_SAMP;
    int* pe = pos + (size_t)e * N_SAMP;
    for (int base = 0; base < N_SAMP; base += 256) {
        const int n = base + t;
        const bool f = gidx[n] >= e;
        unsigned long long m = __ballot(f);
        int rank = __popcll(m & ((1ULL << lane) - 1ULL));
        if (lane == 0) wbase[wave] = __popcll(m);
        __syncthreads();
        int wb = 0;
        #pragma unroll
        for (int w = 0; w < 4; w++) if (w < wave) wb += wbase[w];
        int tot = wbase[0] + wbase[1] + wbase[2] + wbase[3];
        int o = running + wb + rank;
        if (f) { le[o] = n; pe[n] = o; }
        __syncthreads();
        if (t == 0) running += tot;
        __syncthreads();
    }
    const int c = running;
    if (t == 0) cnt[e] = c;
    const int padded = (c + 255) & ~255;
    for (int i = c + t; i < padded && i < N_SAMP; i += 256) le[i] = 0;
}

// ================= 256x256 8-phase bf16 MFMA GEMM (T1+T2+T3+T4+T5) =================
// C[i][m] = relu(A[row(i),:] . BT[m,:] + bias[m]),  BT: [M][K], BK=64, 8 waves (2Mx4N).
// LDS 128KB: 2 buf x {A half0, A half1, B half0, B half1} x 16KB, st_16x32 XOR swizzle
// (linear gll16 dest + pre-swizzled global source + swizzled ds_read, rule #21).
// Grid: (M/256=8) x (N/256=32) = 256 blocks; mb=bid&7 -> per-XCD B-panel residency.
__global__ __launch_bounds__(512, 2) void gemm256(
    const unsigned short* __restrict__ A, const unsigned short* __restrict__ BT,
    const float* __restrict__ bias, unsigned short* __restrict__ C,
    int K, int M, const int* __restrict__ rowlist, const int* __restrict__ cntp) {
    extern __shared__ unsigned short lds_[];   // 131072 bytes
    const int cnt = *cntp;
    const int bid = blockIdx.x;
    const int mb = bid & 7, nb = bid >> 3;
    const int n0 = nb * 256;
    if (n0 >= cnt) return;
    const int m0 = mb * 256;
    const int t = threadIdx.x;
    const int w = t >> 6, lane = t & 63;
    const int wm = w >> 2, wn = w & 3;          // wave -> (sample-half, m-quarter)
    const int lrow = lane & 15, kg = lane >> 4;

    // staging geometry: thread covers chunks t and t+512 of each 16KB half-tile;
    // source address pre-swizzled so that swizzled ds_read sees element (r,c).
    int rr[2], cb[2];
    #pragma unroll
    for (int q = 0; q < 2; q++) {
        int P = (t + q * 512) * 16;
        int Ps = P ^ (((P >> 9) & 1) << 5);     // st_16x32 involution
        rr[q] = Ps >> 7;                        // row within 128-row half
        cb[q] = Ps & 127;                       // byte within 128B row
    }
    int gA[2][2], gB[2][2];
    #pragma unroll
    for (int h = 0; h < 2; h++)
        #pragma unroll
        for (int q = 0; q < 2; q++) {
            int r = n0 + h * 128 + rr[q];
            gA[h][q] = rowlist ? rowlist[r] : r;
            gB[h][q] = m0 + h * 128 + rr[q];
        }

    auto stageA = [&](int buf, int h, int kt) {
        #pragma unroll
        for (int q = 0; q < 2; q++) {
            const char* src = (const char*)(A + (size_t)gA[h][q] * K) + kt * 128 + cb[q];
            gll16(src, &lds_[buf * 32768 + h * 8192 + q * 4096 + w * 512]);
        }
    };
    auto stageB = [&](int buf, int h, int kt) {
        #pragma unroll
        for (int q = 0; q < 2; q++) {
            const char* src = (const char*)(BT + (size_t)gB[h][q] * K) + kt * 128 + cb[q];
            gll16(src, &lds_[buf * 32768 + 16384 + h * 8192 + q * 4096 + w * 512]);
        }
    };
    auto ldA = [&](int buf, int i, int kk) -> bf16x8 {
        int byte = (i * 16 + lrow) * 128 + (kk * 32 + kg * 8) * 2;
        byte ^= ((byte >> 9) & 1) << 5;
        return *(const bf16x8*)&lds_[buf * 32768 + wm * 8192 + (byte >> 1)];
    };
    auto ldB = [&](int buf, int j, int kk) -> bf16x8 {
        int byte = ((wn & 1) * 64 + j * 16 + lrow) * 128 + (kk * 32 + kg * 8) * 2;
        byte ^= ((byte >> 9) & 1) << 5;
        return *(const bf16x8*)&lds_[buf * 32768 + 16384 + (wn >> 1) * 8192 + (byte >> 1)];
    };

    f32x4 acc[8][4];
    #pragma unroll
    for (int i = 0; i < 8; i++)
        #pragma unroll
        for (int j = 0; j < 4; j++) acc[i][j] = (f32x4){0.f, 0.f, 0.f, 0.f};

    const int nt = K >> 6;   // >= 3 always here (16 or 32)

    // prologue: tile0 all 4 halves + tile1 {A0,A1,B0}; vmcnt(6) retires tile0 exactly.
    stageA(0, 0, 0); stageA(0, 1, 0); stageB(0, 0, 0); stageB(0, 1, 0);
    stageA(1, 0, 1); stageA(1, 1, 1); stageB(1, 0, 1);
    asm volatile("s_waitcnt vmcnt(6)" ::: "memory");
    __builtin_amdgcn_s_barrier();

    bf16x8 af[8][2], bf[2][2];
    for (int kt = 0; kt < nt; ++kt) {
        const int buf = kt & 1;
        // ---- phase 0: quadrant i0-3 x j0-1 (12 ds_reads); stage B1(t+1) -> buf^1
        #pragma unroll
        for (int i = 0; i < 4; i++) { af[i][0] = ldA(buf, i, 0); af[i][1] = ldA(buf, i, 1); }
        #pragma unroll
        for (int j = 0; j < 2; j++) { bf[j][0] = ldB(buf, j, 0); bf[j][1] = ldB(buf, j, 1); }
        if (kt + 1 < nt) stageB(buf ^ 1, 1, kt + 1);
        __builtin_amdgcn_s_barrier();
        __builtin_amdgcn_s_setprio(1);
        #pragma unroll
        for (int i = 0; i < 4; i++)
            #pragma unroll
            for (int j = 0; j < 2; j++) {
                acc[i][j] = MFMA16(af[i][0], bf[j][0], acc[i][j], 0, 0, 0);
                acc[i][j] = MFMA16(af[i][1], bf[j][1], acc[i][j], 0, 0, 0);
            }
        __builtin_amdgcn_s_setprio(0);
        __builtin_amdgcn_s_barrier();
        // ---- phase 1: i4-7 x j0-1 (8 ds_reads); A of this tile fully read after this phase
        #pragma unroll
        for (int i = 4; i < 8; i++) { af[i][0] = ldA(buf, i, 0); af[i][1] = ldA(buf, i, 1); }
        __builtin_amdgcn_s_barrier();
        __builtin_amdgcn_s_setprio(1);
        #pragma unroll
        for (int i = 4; i < 8; i++)
            #pragma unroll
            for (int j = 0; j < 2; j++) {
                acc[i][j] = MFMA16(af[i][0], bf[j][0], acc[i][j], 0, 0, 0);
                acc[i][j] = MFMA16(af[i][1], bf[j][1], acc[i][j], 0, 0, 0);
            }
        __builtin_amdgcn_s_setprio(0);
        __builtin_amdgcn_s_barrier();
        // ---- phase 2: i0-3 x j2-3 (4 ds_reads); stage A0,A1(t+2) -> same buf (A reads done)
        #pragma unroll
        for (int j = 0; j < 2; j++) { bf[j][0] = ldB(buf, 2 + j, 0); bf[j][1] = ldB(buf, 2 + j, 1); }
        if (kt + 2 < nt) { stageA(buf, 0, kt + 2); stageA(buf, 1, kt + 2); }
        __builtin_amdgcn_s_barrier();
        __builtin_amdgcn_s_setprio(1);
        #pragma unroll
        for (int i = 0; i < 4; i++)
            #pragma unroll
            for (int j = 0; j < 2; j++) {
                acc[i][2 + j] = MFMA16(af[i][0], bf[j][0], acc[i][2 + j], 0, 0, 0);
                acc[i][2 + j] = MFMA16(af[i][1], bf[j][1], acc[i][2 + j], 0, 0, 0);
            }
        __builtin_amdgcn_s_setprio(0);
        __builtin_amdgcn_s_barrier();
        // ---- phase 3: i4-7 x j2-3 (0 ds_reads); stage B0(t+2) (B reads done after ph2)
        if (kt + 2 < nt) stageB(buf, 0, kt + 2);
        __builtin_amdgcn_s_barrier();
        __builtin_amdgcn_s_setprio(1);
        #pragma unroll
        for (int i = 4; i < 8; i++)
            #pragma unroll
            for (int j = 0; j < 2; j++) {
                acc[i][2 + j] = MFMA16(af[i][0], bf[j][0], acc[i][2 + j], 0, 0, 0);
                acc[i][2 + j] = MFMA16(af[i][1], bf[j][1], acc[i][2 + j], 0, 0, 0);
            }
        __builtin_amdgcn_s_setprio(0);
        // K-tile boundary: counted vmcnt (3 half-tiles = 6 loads in flight), then barrier
        if (kt < nt - 2) asm volatile("s_waitcnt vmcnt(6)" ::: "memory");
        else             asm volatile("s_waitcnt vmcnt(0)" ::: "memory");
        __builtin_amdgcn_s_barrier();
    }

    // epilogue: C/D layout col=lane&15, row=(lane>>4)*4+q  (m89-verified)
    float bv[4];
    #pragma unroll
    for (int j = 0; j < 4; j++)
        bv[j] = bias[m0 + wn * 64 + j * 16 + lrow];
    #pragma unroll
    for (int i = 0; i < 8; i++) {
        const int srow0 = n0 + wm * 128 + i * 16 + kg * 4;
        #pragma unroll
        for (int j = 0; j < 4; j++) {
            const int col = m0 + wn * 64 + j * 16 + lrow;
            #pragma unroll
            for (int q = 0; q < 4; q++) {
                if (srow0 + q < cnt) {
                    float x = acc[i][j][q] + bv[j];
                    C[(size_t)(srow0 + q) * M + col] = f2b(fmaxf(x, 0.f));
                }
            }
        }
    }
}

// ---------------- Gram-Schmidt + gather: one wave per sample (compact obf via pos) ------------
__global__ void gs_kernel(const unsigned short* __restrict__ eo, const float* __restrict__ gval,
                          const int* __restrict__ gidx, const int* __restrict__ pos,
                          float* __restrict__ dout) {
    const int t = threadIdx.x, wave = t >> 6, lane = t & 63;
    const int n = blockIdx.x * 4 + wave;
    const int idx = gidx[n];
    const float g = gval[n];

    float v[32], b0[32], b1[32], b2[32];

    auto loadv = [&](float* dst, int e) {
        const size_t row = pos[(size_t)e * N_SAMP + n];
        const unsigned short* p = eo + ((size_t)e * N_SAMP + row) * HID + lane * 8;
        #pragma unroll
        for (int c = 0; c < 4; c++) {
            uint4 u = *(const uint4*)(p + c * 512);
            const unsigned short* us = (const unsigned short*)&u;
            #pragma unroll
            for (int j = 0; j < 8; j++) dst[c * 8 + j] = b2f(us[j]);
        }
    };
    auto wdot = [&](const float* x, const float* y) -> float {
        float s = 0.f;
        #pragma unroll
        for (int k = 0; k < 32; k++) s += x[k] * y[k];
        #pragma unroll
        for (int o = 32; o; o >>= 1) s += __shfl_xor(s, o);
        return s;
    };
    auto storev = [&](const float* b) {
        float* o = dout + (size_t)n * HID + lane * 8;
        #pragma unroll
        for (int c = 0; c < 4; c++) {
            float4 x0, x1;
            x0.x = g * b[c * 8 + 0]; x0.y = g * b[c * 8 + 1];
            x0.z = g * b[c * 8 + 2]; x0.w = g * b[c * 8 + 3];
            x1.x = g * b[c * 8 + 4]; x1.y = g * b[c * 8 + 5];
            x1.z = g * b[c * 8 + 6]; x1.w = g * b[c * 8 + 7];
            *(float4*)(o + c * 512) = x0;
            *(float4*)(o + c * 512 + 4) = x1;
        }
    };

    loadv(v, 0);
    float inv = 1.f / sqrtf(wdot(v, v));
    #pragma unroll
    for (int k = 0; k < 32; k++) b0[k] = v[k] * inv;
    if (idx == 0) { storev(b0); return; }
    loadv(v, 1);
    {
        float cc0 = wdot(v, b0);
        #pragma unroll
        for (int k = 0; k < 32; k++) v[k] -= cc0 * b0[k];
        inv = 1.f / sqrtf(wdot(v, v));
        #pragma unroll
        for (int k = 0; k < 32; k++) b1[k] = v[k] * inv;
    }
    if (idx == 1) { storev(b1); return; }
    loadv(v, 2);
    {
        float cc0 = wdot(v, b0);
        float cc1 = wdot(v, b1);
        #pragma unroll
        for (int k = 0; k < 32; k++) v[k] -= cc0 * b0[k] + cc1 * b1[k];
        inv = 1.f / sqrtf(wdot(v, v));
        #pragma unroll
        for (int k = 0; k < 32; k++) b2[k] = v[k] * inv;
    }
    if (idx == 2) { storev(b2); return; }
    loadv(v, 3);
    {
        float cc0 = wdot(v, b0);
        float cc1 = wdot(v, b1);
        float cc2 = wdot(v, b2);
        #pragma unroll
        for (int k = 0; k < 32; k++) v[k] -= cc0 * b0[k] + cc1 * b1[k] + cc2 * b2[k];
        inv = 1.f / sqrtf(wdot(v, v));
        #pragma unroll
        for (int k = 0; k < 32; k++) v[k] *= inv;
    }
    storev(v);
}

extern "C" void kernel_launch(void* const* d_in, const int* in_sizes, int n_in,
                              void* d_out, int out_size, void* d_ws, size_t ws_size,
                              hipStream_t stream) {
    const float* bb   = (const float*)d_in[0];
    const int*   task = (const int*)d_in[1];
    const float* temb = (const float*)d_in[2];
    const float* rm   = (const float*)d_in[3];
    const float* W1   = (const float*)d_in[4];
    const float* b1   = (const float*)d_in[5];
    const float* W2   = (const float*)d_in[6];
    const float* b2   = (const float*)d_in[7];
    float* out = (float*)d_out;

    // workspace layout (bytes) -- total ~197.5 MB (proven safe)
    char* ws = (char*)d_ws;
    unsigned short* obf  = (unsigned short*)(ws + 0);           // 128 MB: [E][N][HID] bf16 (compact rows)
    unsigned short* Abf  = (unsigned short*)(ws + 134217728);   //  16 MB: [N][IN_DIM] bf16
    unsigned short* hbf  = (unsigned short*)(ws + 150994944);   //  32 MB: [N][HID] bf16 (per-expert, compact)
    unsigned short* W1T  = (unsigned short*)(ws + 184549376);   //   4 MB
    unsigned short* W2T  = (unsigned short*)(ws + 188743680);   //   8 MB
    float*          gv   = (float*)(ws + 197132288);            //  32 KB
    int*            gi   = (int*)(ws + 197165056);              //  32 KB
    int*            list = (int*)(ws + 197197824);              // 128 KB: [E][N]
    int*            pos  = (int*)(ws + 197328896);              // 128 KB: [E][N]
    int*            cnt  = (int*)(ws + 197459968);              //  16 B

    conv_bf16<<<(N_SAMP * IN_DIM) / 1024, 256, 0, stream>>>(bb, Abf, N_SAMP * IN_DIM);
    router_kernel<<<N_SAMP / 4, 256, 0, stream>>>(bb, task, temb, rm, gv, gi,
                                                  out + (size_t)N_SAMP * HID);
    compact_kernel<<<NE, 256, 0, stream>>>(gi, list, pos, cnt);

    const int gemm_blocks = (HID / 256) * (N_SAMP / 256);   // 8 * 32 = 256
    const size_t lds_bytes = 131072;
    for (int e = 0; e < NE; ++e) {
        transpose_conv<<<dim3(IN_DIM / 64, HID / 64), 256, 0, stream>>>(
            W1 + (size_t)e * IN_DIM * HID, W1T, IN_DIM, HID);
        gemm256<<<gemm_blocks, 512, lds_bytes, stream>>>(
            Abf, W1T, b1 + (size_t)e * HID, hbf, IN_DIM, HID,
            list + (size_t)e * N_SAMP, cnt + e);
        transpose_conv<<<dim3(HID / 64, HID / 64), 256, 0, stream>>>(
            W2 + (size_t)e * HID * HID, W2T, HID, HID);
        gemm256<<<gemm_blocks, 512, lds_bytes, stream>>>(
            hbf, W2T, b2 + (size_t)e * HID, obf + (size_t)e * N_SAMP * HID, HID, HID,
            nullptr, cnt + e);
    }

    gs_kernel<<<N_SAMP / 4, 256, 0, stream>>>(obf, gv, gi, pos, out);
}

// Round 6
// 565.710 us; speedup vs baseline: 1.1583x; 1.1583x over previous
//
#include <hip/hip_runtime.h>
#include <hip/hip_bf16.h>
#include <cstdint>

#define N_SAMP 8192
#define IN_DIM 1024
#define HID    2048
#define NE     4

typedef __attribute__((ext_vector_type(8))) __bf16 bf16x8;
typedef __attribute__((ext_vector_type(4))) float  f32x4;

#define MFMA16 __builtin_amdgcn_mfma_f32_16x16x32_bf16

__device__ __forceinline__ unsigned short f2b(float f) {
    unsigned u = __float_as_uint(f);
    u += 0x7fff + ((u >> 16) & 1);          // RNE, finite inputs only
    return (unsigned short)(u >> 16);
}
__device__ __forceinline__ float b2f(unsigned short s) {
    return __uint_as_float(((unsigned)s) << 16);
}

// async global->LDS, 16B per lane; LDS dest is wave-uniform base (+lane*16 by HW)
__device__ __forceinline__ void gll16(const void* g, void* l) {
    __builtin_amdgcn_global_load_lds(
        (const __attribute__((address_space(1))) void*)g,
        (__attribute__((address_space(3))) void*)l,
        16, 0, 0);
}

// LDS byte swizzle for 128B-row tiles: bits 4-6 ^= row bits 0-2 (byte bits 7-9).
// Involution; keeps 16B alignment; spreads a 16-row column-slice across all 8
// 16B slots -> conflict-free ds_read_b128 (each bank serves exactly 8 words).
__device__ __forceinline__ int swz(int byte) {
    return byte ^ (((byte >> 7) & 7) << 4);
}

// ---------------- f32 -> bf16 elementwise ----------------
__global__ void conv_bf16(const float* __restrict__ s, unsigned short* __restrict__ d, int n) {
    int i = (blockIdx.x * blockDim.x + threadIdx.x) * 4;
    if (i >= n) return;
    float4 v = *(const float4*)&s[i];
    ushort4 o;
    o.x = f2b(v.x); o.y = f2b(v.y); o.z = f2b(v.z); o.w = f2b(v.w);
    *(ushort4*)&d[i] = o;
}

// ---------------- transpose + convert: src [K][M] f32 -> dst [M][K] bf16 ----------------
__global__ void transpose_conv(const float* __restrict__ src, unsigned short* __restrict__ dst,
                               int K, int M) {
    __shared__ float tile[64][65];
    const int k0 = blockIdx.x * 64, m0 = blockIdx.y * 64;
    const int t  = threadIdx.x;
    const int tc = t & 15, tr = t >> 4;
    const float* s = src + (size_t)k0 * M + m0;
    #pragma unroll
    for (int r = tr; r < 64; r += 16) {
        float4 v = *(const float4*)&s[(size_t)r * M + tc * 4];
        tile[r][tc * 4 + 0] = v.x; tile[r][tc * 4 + 1] = v.y;
        tile[r][tc * 4 + 2] = v.z; tile[r][tc * 4 + 3] = v.w;
    }
    __syncthreads();
    unsigned short* d = dst + (size_t)m0 * K + k0;
    #pragma unroll
    for (int r = tr; r < 64; r += 16) {
        ushort4 o;
        o.x = f2b(tile[tc * 4 + 0][r]); o.y = f2b(tile[tc * 4 + 1][r]);
        o.z = f2b(tile[tc * 4 + 2][r]); o.w = f2b(tile[tc * 4 + 3][r]);
        *(ushort4*)&d[(size_t)r * K + tc * 4] = o;
    }
}

// ---------------- router: fp32 logits, softmax, first-max argmax, reg_loss ----------------
__global__ void router_kernel(const float* __restrict__ bb, const int* __restrict__ task,
                              const float* __restrict__ temb, const float* __restrict__ rm,
                              float* __restrict__ gval, int* __restrict__ gidx,
                              float* __restrict__ regout) {
    const int t = threadIdx.x, wave = t >> 6, lane = t & 63;
    const int n = blockIdx.x * 4 + wave;
    const int tk = task[n];
    float a0 = 0.f, a1 = 0.f, a2 = 0.f, a3 = 0.f;
    for (int i = lane; i < IN_DIM + 100; i += 64) {
        float x = (i < IN_DIM) ? bb[(size_t)n * IN_DIM + i] : temb[tk * 100 + (i - IN_DIM)];
        float4 r = *(const float4*)&rm[i * 4];
        a0 += x * r.x; a1 += x * r.y; a2 += x * r.z; a3 += x * r.w;
    }
    #pragma unroll
    for (int o = 32; o; o >>= 1) {
        a0 += __shfl_xor(a0, o); a1 += __shfl_xor(a1, o);
        a2 += __shfl_xor(a2, o); a3 += __shfl_xor(a3, o);
    }
    if (lane == 0) {
        float l[4] = {a0, a1, a2, a3};
        float mx = fmaxf(fmaxf(l[0], l[1]), fmaxf(l[2], l[3]));
        float ex[4], s = 0.f;
        #pragma unroll
        for (int j = 0; j < 4; j++) { ex[j] = expf(l[j] - mx); s += ex[j]; }
        int bi = 0; float bw = ex[0];
        #pragma unroll
        for (int j = 1; j < 4; j++) if (ex[j] > bw) { bw = ex[j]; bi = j; }
        float g = bw / s;
        gval[n] = g;
        gidx[n] = bi;
        regout[n] = -0.0025f * (logf(g + 1e-6f) + 3.0f * logf(1e-6f));
    }
}

// ---------------- per-expert compaction: list_e = {n : idx[n] >= e}; pad to mult 256 --------
__global__ void compact_kernel(const int* __restrict__ gidx, int* __restrict__ list,
                               int* __restrict__ pos, int* __restrict__ cnt) {
    const int e = blockIdx.x;
    const int t = threadIdx.x, lane = t & 63, wave = t >> 6;
    __shared__ int wbase[4];
    __shared__ int running;
    if (t == 0) running = 0;
    __syncthreads();
    int* le = list + (size_t)e * N_SAMP;
    int* pe = pos + (size_t)e * N_SAMP;
    for (int base = 0; base < N_SAMP; base += 256) {
        const int n = base + t;
        const bool f = gidx[n] >= e;
        unsigned long long m = __ballot(f);
        int rank = __popcll(m & ((1ULL << lane) - 1ULL));
        if (lane == 0) wbase[wave] = __popcll(m);
        __syncthreads();
        int wb = 0;
        #pragma unroll
        for (int w = 0; w < 4; w++) if (w < wave) wb += wbase[w];
        int tot = wbase[0] + wbase[1] + wbase[2] + wbase[3];
        int o = running + wb + rank;
        if (f) { le[o] = n; pe[n] = o; }
        __syncthreads();
        if (t == 0) running += tot;
        __syncthreads();
    }
    const int c = running;
    if (t == 0) cnt[e] = c;
    const int padded = (c + 255) & ~255;
    for (int i = c + t; i < padded && i < N_SAMP; i += 256) le[i] = 0;
}

// ================= 256x256 8-phase bf16 MFMA GEMM (T1+T2+T3+T4+T5) =================
// C[i][m] = relu(A[row(i),:] . BT[m,:] + bias[m]),  BT: [M][K], BK=64, 8 waves (2Mx4N).
// LDS 128KB: 2 buf x {A half0, A half1, B half0, B half1} x 16KB, full 8-slot XOR swizzle
// (linear gll16 dest + pre-swizzled global source + swizzled ds_read, rule #21).
// Grid: (M/256=8) x (N/256=32) = 256 blocks; mb=bid&7 -> per-XCD B-panel residency.
__global__ __launch_bounds__(512, 2) void gemm256(
    const unsigned short* __restrict__ A, const unsigned short* __restrict__ BT,
    const float* __restrict__ bias, unsigned short* __restrict__ C,
    int K, int M, const int* __restrict__ rowlist, const int* __restrict__ cntp) {
    extern __shared__ unsigned short lds_[];   // 131072 bytes
    const int cnt = *cntp;
    const int bid = blockIdx.x;
    const int mb = bid & 7, nb = bid >> 3;
    const int n0 = nb * 256;
    if (n0 >= cnt) return;
    const int m0 = mb * 256;
    const int t = threadIdx.x;
    const int w = t >> 6, lane = t & 63;
    const int wm = w >> 2, wn = w & 3;          // wave -> (sample-half, m-quarter)
    const int lrow = lane & 15, kg = lane >> 4;

    // staging geometry: thread covers chunks t and t+512 of each 16KB half-tile;
    // source address pre-swizzled so that swizzled ds_read sees element (r,c).
    int rr[2], cb[2];
    #pragma unroll
    for (int q = 0; q < 2; q++) {
        int P = (t + q * 512) * 16;
        int Ps = swz(P);
        rr[q] = Ps >> 7;                        // row within 128-row half
        cb[q] = Ps & 127;                       // byte within 128B row
    }
    int gA[2][2], gB[2][2];
    #pragma unroll
    for (int h = 0; h < 2; h++)
        #pragma unroll
        for (int q = 0; q < 2; q++) {
            int r = n0 + h * 128 + rr[q];
            gA[h][q] = rowlist ? rowlist[r] : r;
            gB[h][q] = m0 + h * 128 + rr[q];
        }

    auto stageA = [&](int buf, int h, int kt) {
        #pragma unroll
        for (int q = 0; q < 2; q++) {
            const char* src = (const char*)(A + (size_t)gA[h][q] * K) + kt * 128 + cb[q];
            gll16(src, &lds_[buf * 32768 + h * 8192 + q * 4096 + w * 512]);
        }
    };
    auto stageB = [&](int buf, int h, int kt) {
        #pragma unroll
        for (int q = 0; q < 2; q++) {
            const char* src = (const char*)(BT + (size_t)gB[h][q] * K) + kt * 128 + cb[q];
            gll16(src, &lds_[buf * 32768 + 16384 + h * 8192 + q * 4096 + w * 512]);
        }
    };
    auto ldA = [&](int buf, int i, int kk) -> bf16x8 {
        int byte = (i * 16 + lrow) * 128 + (kk * 32 + kg * 8) * 2;
        byte = swz(byte);
        return *(const bf16x8*)&lds_[buf * 32768 + wm * 8192 + (byte >> 1)];
    };
    auto ldB = [&](int buf, int j, int kk) -> bf16x8 {
        int byte = ((wn & 1) * 64 + j * 16 + lrow) * 128 + (kk * 32 + kg * 8) * 2;
        byte = swz(byte);
        return *(const bf16x8*)&lds_[buf * 32768 + 16384 + (wn >> 1) * 8192 + (byte >> 1)];
    };

    f32x4 acc[8][4];
    #pragma unroll
    for (int i = 0; i < 8; i++)
        #pragma unroll
        for (int j = 0; j < 4; j++) acc[i][j] = (f32x4){0.f, 0.f, 0.f, 0.f};

    const int nt = K >> 6;   // >= 3 always here (16 or 32)

    // prologue: tile0 all 4 halves + tile1 {A0,A1,B0}; vmcnt(6) retires tile0 exactly.
    stageA(0, 0, 0); stageA(0, 1, 0); stageB(0, 0, 0); stageB(0, 1, 0);
    stageA(1, 0, 1); stageA(1, 1, 1); stageB(1, 0, 1);
    asm volatile("s_waitcnt vmcnt(6)" ::: "memory");
    __builtin_amdgcn_s_barrier();

    bf16x8 af[8][2], bf[2][2];
    for (int kt = 0; kt < nt; ++kt) {
        const int buf = kt & 1;
        // ---- phase 0: quadrant i0-3 x j0-1 (12 ds_reads); stage B1(t+1) -> buf^1
        #pragma unroll
        for (int i = 0; i < 4; i++) { af[i][0] = ldA(buf, i, 0); af[i][1] = ldA(buf, i, 1); }
        #pragma unroll
        for (int j = 0; j < 2; j++) { bf[j][0] = ldB(buf, j, 0); bf[j][1] = ldB(buf, j, 1); }
        if (kt + 1 < nt) stageB(buf ^ 1, 1, kt + 1);
        __builtin_amdgcn_s_barrier();
        __builtin_amdgcn_s_setprio(1);
        #pragma unroll
        for (int i = 0; i < 4; i++)
            #pragma unroll
            for (int j = 0; j < 2; j++) {
                acc[i][j] = MFMA16(af[i][0], bf[j][0], acc[i][j], 0, 0, 0);
                acc[i][j] = MFMA16(af[i][1], bf[j][1], acc[i][j], 0, 0, 0);
            }
        __builtin_amdgcn_s_setprio(0);
        __builtin_amdgcn_s_barrier();
        // ---- phase 1: i4-7 x j0-1 (8 ds_reads); A of this tile fully read after this phase
        #pragma unroll
        for (int i = 4; i < 8; i++) { af[i][0] = ldA(buf, i, 0); af[i][1] = ldA(buf, i, 1); }
        __builtin_amdgcn_s_barrier();
        __builtin_amdgcn_s_setprio(1);
        #pragma unroll
        for (int i = 4; i < 8; i++)
            #pragma unroll
            for (int j = 0; j < 2; j++) {
                acc[i][j] = MFMA16(af[i][0], bf[j][0], acc[i][j], 0, 0, 0);
                acc[i][j] = MFMA16(af[i][1], bf[j][1], acc[i][j], 0, 0, 0);
            }
        __builtin_amdgcn_s_setprio(0);
        __builtin_amdgcn_s_barrier();
        // ---- phase 2: i0-3 x j2-3 (4 ds_reads); stage A0,A1(t+2) -> same buf (A reads done)
        #pragma unroll
        for (int j = 0; j < 2; j++) { bf[j][0] = ldB(buf, 2 + j, 0); bf[j][1] = ldB(buf, 2 + j, 1); }
        if (kt + 2 < nt) { stageA(buf, 0, kt + 2); stageA(buf, 1, kt + 2); }
        __builtin_amdgcn_s_barrier();
        __builtin_amdgcn_s_setprio(1);
        #pragma unroll
        for (int i = 0; i < 4; i++)
            #pragma unroll
            for (int j = 0; j < 2; j++) {
                acc[i][2 + j] = MFMA16(af[i][0], bf[j][0], acc[i][2 + j], 0, 0, 0);
                acc[i][2 + j] = MFMA16(af[i][1], bf[j][1], acc[i][2 + j], 0, 0, 0);
            }
        __builtin_amdgcn_s_setprio(0);
        __builtin_amdgcn_s_barrier();
        // ---- phase 3: i4-7 x j2-3 (0 ds_reads); stage B0(t+2) (B reads done after ph2)
        if (kt + 2 < nt) stageB(buf, 0, kt + 2);
        __builtin_amdgcn_s_barrier();
        __builtin_amdgcn_s_setprio(1);
        #pragma unroll
        for (int i = 4; i < 8; i++)
            #pragma unroll
            for (int j = 0; j < 2; j++) {
                acc[i][2 + j] = MFMA16(af[i][0], bf[j][0], acc[i][2 + j], 0, 0, 0);
                acc[i][2 + j] = MFMA16(af[i][1], bf[j][1], acc[i][2 + j], 0, 0, 0);
            }
        __builtin_amdgcn_s_setprio(0);
        // K-tile boundary: counted vmcnt (3 half-tiles = 6 loads in flight), then barrier
        if (kt < nt - 2) asm volatile("s_waitcnt vmcnt(6)" ::: "memory");
        else             asm volatile("s_waitcnt vmcnt(0)" ::: "memory");
        __builtin_amdgcn_s_barrier();
    }

    // epilogue: C/D layout col=lane&15, row=(lane>>4)*4+q  (m89-verified)
    float bv[4];
    #pragma unroll
    for (int j = 0; j < 4; j++)
        bv[j] = bias[m0 + wn * 64 + j * 16 + lrow];
    #pragma unroll
    for (int i = 0; i < 8; i++) {
        const int srow0 = n0 + wm * 128 + i * 16 + kg * 4;
        #pragma unroll
        for (int j = 0; j < 4; j++) {
            const int col = m0 + wn * 64 + j * 16 + lrow;
            #pragma unroll
            for (int q = 0; q < 4; q++) {
                if (srow0 + q < cnt) {
                    float x = acc[i][j][q] + bv[j];
                    C[(size_t)(srow0 + q) * M + col] = f2b(fmaxf(x, 0.f));
                }
            }
        }
    }
}

// ---------------- Gram-Schmidt + gather: one wave per sample (compact obf via pos) ------------
__global__ void gs_kernel(const unsigned short* __restrict__ eo, const float* __restrict__ gval,
                          const int* __restrict__ gidx, const int* __restrict__ pos,
                          float* __restrict__ dout) {
    const int t = threadIdx.x, wave = t >> 6, lane = t & 63;
    const int n = blockIdx.x * 4 + wave;
    const int idx = gidx[n];
    const float g = gval[n];

    float v[32], b0[32], b1[32], b2[32];

    auto loadv = [&](float* dst, int e) {
        const size_t row = pos[(size_t)e * N_SAMP + n];
        const unsigned short* p = eo + ((size_t)e * N_SAMP + row) * HID + lane * 8;
        #pragma unroll
        for (int c = 0; c < 4; c++) {
            uint4 u = *(const uint4*)(p + c * 512);
            const unsigned short* us = (const unsigned short*)&u;
            #pragma unroll
            for (int j = 0; j < 8; j++) dst[c * 8 + j] = b2f(us[j]);
        }
    };
    auto wdot = [&](const float* x, const float* y) -> float {
        float s = 0.f;
        #pragma unroll
        for (int k = 0; k < 32; k++) s += x[k] * y[k];
        #pragma unroll
        for (int o = 32; o; o >>= 1) s += __shfl_xor(s, o);
        return s;
    };
    auto storev = [&](const float* b) {
        float* o = dout + (size_t)n * HID + lane * 8;
        #pragma unroll
        for (int c = 0; c < 4; c++) {
            float4 x0, x1;
            x0.x = g * b[c * 8 + 0]; x0.y = g * b[c * 8 + 1];
            x0.z = g * b[c * 8 + 2]; x0.w = g * b[c * 8 + 3];
            x1.x = g * b[c * 8 + 4]; x1.y = g * b[c * 8 + 5];
            x1.z = g * b[c * 8 + 6]; x1.w = g * b[c * 8 + 7];
            *(float4*)(o + c * 512) = x0;
            *(float4*)(o + c * 512 + 4) = x1;
        }
    };

    loadv(v, 0);
    float inv = 1.f / sqrtf(wdot(v, v));
    #pragma unroll
    for (int k = 0; k < 32; k++) b0[k] = v[k] * inv;
    if (idx == 0) { storev(b0); return; }
    loadv(v, 1);
    {
        float cc0 = wdot(v, b0);
        #pragma unroll
        for (int k = 0; k < 32; k++) v[k] -= cc0 * b0[k];
        inv = 1.f / sqrtf(wdot(v, v));
        #pragma unroll
        for (int k = 0; k < 32; k++) b1[k] = v[k] * inv;
    }
    if (idx == 1) { storev(b1); return; }
    loadv(v, 2);
    {
        float cc0 = wdot(v, b0);
        float cc1 = wdot(v, b1);
        #pragma unroll
        for (int k = 0; k < 32; k++) v[k] -= cc0 * b0[k] + cc1 * b1[k];
        inv = 1.f / sqrtf(wdot(v, v));
        #pragma unroll
        for (int k = 0; k < 32; k++) b2[k] = v[k] * inv;
    }
    if (idx == 2) { storev(b2); return; }
    loadv(v, 3);
    {
        float cc0 = wdot(v, b0);
        float cc1 = wdot(v, b1);
        float cc2 = wdot(v, b2);
        #pragma unroll
        for (int k = 0; k < 32; k++) v[k] -= cc0 * b0[k] + cc1 * b1[k] + cc2 * b2[k];
        inv = 1.f / sqrtf(wdot(v, v));
        #pragma unroll
        for (int k = 0; k < 32; k++) v[k] *= inv;
    }
    storev(v);
}

extern "C" void kernel_launch(void* const* d_in, const int* in_sizes, int n_in,
                              void* d_out, int out_size, void* d_ws, size_t ws_size,
                              hipStream_t stream) {
    const float* bb   = (const float*)d_in[0];
    const int*   task = (const int*)d_in[1];
    const float* temb = (const float*)d_in[2];
    const float* rm   = (const float*)d_in[3];
    const float* W1   = (const float*)d_in[4];
    const float* b1   = (const float*)d_in[5];
    const float* W2   = (const float*)d_in[6];
    const float* b2   = (const float*)d_in[7];
    float* out = (float*)d_out;

    // workspace layout (bytes) -- total ~197.5 MB (proven safe)
    char* ws = (char*)d_ws;
    unsigned short* obf  = (unsigned short*)(ws + 0);           // 128 MB: [E][N][HID] bf16 (compact rows)
    unsigned short* Abf  = (unsigned short*)(ws + 134217728);   //  16 MB: [N][IN_DIM] bf16
    unsigned short* hbf  = (unsigned short*)(ws + 150994944);   //  32 MB: [N][HID] bf16 (per-expert, compact)
    unsigned short* W1T  = (unsigned short*)(ws + 184549376);   //   4 MB
    unsigned short* W2T  = (unsigned short*)(ws + 188743680);   //   8 MB
    float*          gv   = (float*)(ws + 197132288);            //  32 KB
    int*            gi   = (int*)(ws + 197165056);              //  32 KB
    int*            list = (int*)(ws + 197197824);              // 128 KB: [E][N]
    int*            pos  = (int*)(ws + 197328896);              // 128 KB: [E][N]
    int*            cnt  = (int*)(ws + 197459968);              //  16 B

    conv_bf16<<<(N_SAMP * IN_DIM) / 1024, 256, 0, stream>>>(bb, Abf, N_SAMP * IN_DIM);
    router_kernel<<<N_SAMP / 4, 256, 0, stream>>>(bb, task, temb, rm, gv, gi,
                                                  out + (size_t)N_SAMP * HID);
    compact_kernel<<<NE, 256, 0, stream>>>(gi, list, pos, cnt);

    const int gemm_blocks = (HID / 256) * (N_SAMP / 256);   // 8 * 32 = 256
    const size_t lds_bytes = 131072;
    for (int e = 0; e < NE; ++e) {
        transpose_conv<<<dim3(IN_DIM / 64, HID / 64), 256, 0, stream>>>(
            W1 + (size_t)e * IN_DIM * HID, W1T, IN_DIM, HID);
        gemm256<<<gemm_blocks, 512, lds_bytes, stream>>>(
            Abf, W1T, b1 + (size_t)e * HID, hbf, IN_DIM, HID,
            list + (size_t)e * N_SAMP, cnt + e);
        transpose_conv<<<dim3(HID / 64, HID / 64), 256, 0, stream>>>(
            W2 + (size_t)e * HID * HID, W2T, HID, HID);
        gemm256<<<gemm_blocks, 512, lds_bytes, stream>>>(
            hbf, W2T, b2 + (size_t)e * HID, obf + (size_t)e * N_SAMP * HID, HID, HID,
            nullptr, cnt + e);
    }

    gs_kernel<<<N_SAMP / 4, 256, 0, stream>>>(obf, gv, gi, pos, out);
}